// Round 7
// baseline (416.361 us; speedup 1.0000x reference)
//
#include <hip/hip_runtime.h>
#include <hip/hip_bf16.h>
#include <math.h>

#define D_MODEL 1024
#define D_STATE 16
#define D_CONV 4
#define D_INNER 2048
#define DT_RANK 64
#define L_SEQ 2048
#define N_BATCH 2
#define M_ROWS (N_BATCH * L_SEQ)   // 4096

#define N_CHUNK 32                 // chunks over L
#define CLEN (L_SEQ / N_CHUNK)     // 64 timesteps per chunk

#define XP_KSPLIT 8                // split-K factor for x_proj
#define XP_KLEN (D_INNER / XP_KSPLIT)  // 256
#define OP_KSPLIT 2                // split-K factor for out_proj
#define OP_KLEN (D_INNER / OP_KSPLIT)  // 1024

typedef __attribute__((ext_vector_type(8))) __bf16 bf16x8;
typedef __attribute__((ext_vector_type(4))) float f32x4;

__device__ __forceinline__ unsigned short f2b(float f) {
    unsigned int u = __float_as_uint(f);
    unsigned int r = (u + 0x7fffu + ((u >> 16) & 1u)) >> 16;   // RNE
    return (unsigned short)r;
}
__device__ __forceinline__ float b2f(unsigned short s) {
    return __uint_as_float((unsigned int)s << 16);
}

// addrspace casts for global_load_lds
#define AS1G(p) ((const __attribute__((address_space(1))) void*)(uintptr_t)(p))
#define AS3L(p) ((__attribute__((address_space(3))) void*)(unsigned int)(uintptr_t)(p))

// ---------------------------------------------------------------------------
// Fused fp32 -> bf16 cast of all 5 weight/activation tensors (one launch).
// x_proj_w is padded 96 -> 128 rows (zeros).
// ---------------------------------------------------------------------------
#define N4_HS (M_ROWS * D_MODEL / 4)          // 1048576
#define N4_IP (2 * D_INNER * D_MODEL / 4)     // 2097152
#define N4_OP (D_MODEL * D_INNER / 4)         // 524288
#define N4_XP (128 * D_INNER / 4)             // 65536 (padded)
#define N4_DT (D_INNER * DT_RANK / 4)         // 32768
#define N4_ALL (N4_HS + N4_IP + N4_OP + N4_XP + N4_DT)

__device__ __forceinline__ void cvt4(const float* s, unsigned short* d, int i) {
    const float4 f = ((const float4*)s)[i];
    ushort4 o;
    o.x = f2b(f.x); o.y = f2b(f.y); o.z = f2b(f.z); o.w = f2b(f.w);
    ((ushort4*)d)[i] = o;
}

__global__ __launch_bounds__(256) void cvt_all_kernel(
    const float* __restrict__ hs,  const float* __restrict__ ipw,
    const float* __restrict__ opw, const float* __restrict__ xpw,
    const float* __restrict__ dtw,
    unsigned short* __restrict__ hs_bf,  unsigned short* __restrict__ ipw_bf,
    unsigned short* __restrict__ opw_bf, unsigned short* __restrict__ xpw_bf,
    unsigned short* __restrict__ dtw_bf)
{
    int i = blockIdx.x * 256 + threadIdx.x;
    if (i < N4_HS) { cvt4(hs, hs_bf, i); return; }
    i -= N4_HS;
    if (i < N4_IP) { cvt4(ipw, ipw_bf, i); return; }
    i -= N4_IP;
    if (i < N4_OP) { cvt4(opw, opw_bf, i); return; }
    i -= N4_OP;
    if (i < N4_XP) {
        const int row = (i * 4) >> 11;   // /2048
        ushort4 o;
        if (row < 96) {
            const float4 f = ((const float4*)xpw)[i];
            o.x = f2b(f.x); o.y = f2b(f.y); o.z = f2b(f.z); o.w = f2b(f.w);
        } else { o.x = o.y = o.z = o.w = 0; }
        ((ushort4*)xpw_bf)[i] = o;
        return;
    }
    i -= N4_XP;
    if (i < N4_DT) cvt4(dtw, dtw_bf, i);
}

// ---------------------------------------------------------------------------
// bf16 MFMA GEMM (m97 structure): C[M,N] = A[M,K]*B[N,K]^T.
// CT = float (fp32 out, used for split-K partials) or unsigned short (bf16).
// MODE 0: plain.  MODE 1: softplus(acc + bias[col]).
// Split-K: blockIdx.z selects K-chunk [z*k_len,(z+1)*k_len), C += z*M*N.
// ---------------------------------------------------------------------------
template <int MODE, typename CT>
__global__ __launch_bounds__(256) void gemm_mfma_bt(
    const unsigned short* __restrict__ A, const unsigned short* __restrict__ B,
    CT* __restrict__ C, const float* __restrict__ bias,
    int M, int N, int K, int k_len)
{
    __shared__ unsigned short As[128 * 32];
    __shared__ unsigned short Bs[128 * 32];

    const int tid  = threadIdx.x;
    const int wave = tid >> 6;
    const int lane = tid & 63;
    const int row0 = blockIdx.y * 128;
    const int col0 = blockIdx.x * 128;
    const int kbeg = blockIdx.z * k_len;
    C += (size_t)blockIdx.z * M * N;
    const int wr = (wave >> 1) * 64;
    const int wc = (wave & 1) * 64;
    const int lm = lane & 15;
    const int kg = (lane >> 4) * 8;

    f32x4 acc[4][4];
    #pragma unroll
    for (int i = 0; i < 4; ++i)
        #pragma unroll
        for (int j = 0; j < 4; ++j)
            acc[i][j] = (f32x4){0.f, 0.f, 0.f, 0.f};

    const int c0 = tid;
    const int c1 = tid + 256;
    const int r0_ = c0 >> 2, kq0 = (c0 & 3) * 8;
    const int r1_ = c1 >> 2, kq1 = (c1 & 3) * 8;
    unsigned short* lA0 = As + wave * 512;
    unsigned short* lA1 = As + 2048 + wave * 512;
    unsigned short* lB0 = Bs + wave * 512;
    unsigned short* lB1 = Bs + 2048 + wave * 512;

    for (int k0 = kbeg; k0 < kbeg + k_len; k0 += 32) {
        __syncthreads();
        __builtin_amdgcn_global_load_lds(AS1G(A + (size_t)(row0 + r0_) * K + k0 + kq0), AS3L(lA0), 16, 0, 0);
        __builtin_amdgcn_global_load_lds(AS1G(A + (size_t)(row0 + r1_) * K + k0 + kq1), AS3L(lA1), 16, 0, 0);
        __builtin_amdgcn_global_load_lds(AS1G(B + (size_t)(col0 + r0_) * K + k0 + kq0), AS3L(lB0), 16, 0, 0);
        __builtin_amdgcn_global_load_lds(AS1G(B + (size_t)(col0 + r1_) * K + k0 + kq1), AS3L(lB1), 16, 0, 0);
        __syncthreads();

        bf16x8 af[4], bf[4];
        #pragma unroll
        for (int i = 0; i < 4; ++i) {
            af[i] = *(const bf16x8*)&As[(wr + i * 16 + lm) * 32 + kg];
            bf[i] = *(const bf16x8*)&Bs[(wc + i * 16 + lm) * 32 + kg];
        }
        #pragma unroll
        for (int i = 0; i < 4; ++i)
            #pragma unroll
            for (int j = 0; j < 4; ++j)
                acc[i][j] = __builtin_amdgcn_mfma_f32_16x16x32_bf16(af[i], bf[j], acc[i][j], 0, 0, 0);
    }

    // C/D mapping: col = lane&15, row = (lane>>4)*4 + reg
    #pragma unroll
    for (int j = 0; j < 4; ++j) {
        const int cc = col0 + wc + j * 16 + lm;
        const float bv = (MODE == 1) ? bias[cc] : 0.f;
        #pragma unroll
        for (int i = 0; i < 4; ++i) {
            const int r = row0 + wr + i * 16 + (lane >> 4) * 4;
            #pragma unroll
            for (int v = 0; v < 4; ++v) {
                float val = acc[i][j][v];
                if (MODE == 1) {
                    val += bv;
                    val = (val > 20.f) ? val : log1pf(__expf(val));
                }
                if (sizeof(CT) == 2)
                    C[(size_t)(r + v) * N + cc] = (CT)f2b(val);
                else
                    C[(size_t)(r + v) * N + cc] = (CT)val;
            }
        }
    }
}

// reduce x_proj split-K partials [XP_KSPLIT][M][128] -> xdbl [M][96] fp32
// and dt_bf [M][64] bf16 (columns 0..63).
__global__ __launch_bounds__(256) void xproj_reduce_kernel(
    const float* __restrict__ part, float* __restrict__ xdbl,
    unsigned short* __restrict__ dt_bf)
{
    const int i = blockIdx.x * 256 + threadIdx.x;   // over M * 24
    if (i >= M_ROWS * 24) return;
    const int m  = i / 24;
    const int j4 = (i - m * 24) * 4;
    f32x4 s = *(const f32x4*)(part + (size_t)m * 128 + j4);
    #pragma unroll
    for (int ks = 1; ks < XP_KSPLIT; ++ks)
        s += *(const f32x4*)(part + (size_t)ks * M_ROWS * 128 + (size_t)m * 128 + j4);
    *(f32x4*)(xdbl + (size_t)m * 96 + j4) = s;
    if (j4 < DT_RANK) {
        ushort4 o;
        o.x = f2b(s.x); o.y = f2b(s.y); o.z = f2b(s.z); o.w = f2b(s.w);
        *(ushort4*)(dt_bf + (size_t)m * DT_RANK + j4) = o;
    }
}

// reduce out_proj split-K partials [OP_KSPLIT][M][D_MODEL] -> out (fp32)
__global__ __launch_bounds__(256) void oproj_reduce_kernel(
    const float* __restrict__ part, float* __restrict__ out)
{
    const int i = blockIdx.x * 256 + threadIdx.x;   // over M*D_MODEL/4
    if (i >= M_ROWS * D_MODEL / 4) return;
    f32x4 s = ((const f32x4*)part)[i];
    #pragma unroll
    for (int ks = 1; ks < OP_KSPLIT; ++ks)
        s += ((const f32x4*)part)[(size_t)ks * (M_ROWS * D_MODEL / 4) + i];
    ((f32x4*)out)[i] = s;
}

// ---------------------------------------------------------------------------
// Depthwise causal conv (width 4) + bias + SiLU.  bf16 in (x half of xz),
// bf16 out.
// ---------------------------------------------------------------------------
__global__ __launch_bounds__(256) void conv_silu_kernel(
    const unsigned short* __restrict__ xz_bf, const float* __restrict__ conv_w,
    const float* __restrict__ conv_b, unsigned short* __restrict__ u_bf)
{
    const int idx = blockIdx.x * 256 + threadIdx.x;
    const int c  = idx & (D_INNER - 1);
    const int ml = idx >> 11;
    const int l  = ml & (L_SEQ - 1);
    float acc = conv_b[c];
    const float* w = conv_w + c * D_CONV;
    #pragma unroll
    for (int j = 0; j < D_CONV; ++j) {
        const int ll = l - (D_CONV - 1) + j;
        if (ll >= 0)
            acc = fmaf(b2f(xz_bf[(size_t)(ml - (D_CONV - 1) + j) * (2 * D_INNER) + c]), w[j], acc);
    }
    const float uv = acc / (1.f + __expf(-acc));
    u_bf[(size_t)ml * D_INNER + c] = f2b(uv);
}

// ---------------------------------------------------------------------------
// Sequential-register selective scan.  One lane owns one d channel and all 16
// states in registers.  delta/u/z: bf16; B/C: wave-uniform s_loads (fp32).
// ---------------------------------------------------------------------------
template <int PHASE>
__global__ __launch_bounds__(256) void scan_seq_kernel(
    const unsigned short* __restrict__ delta_bf,
    const unsigned short* __restrict__ u_bf,
    const float* __restrict__ xdbl,  const unsigned short* __restrict__ xz_bf,
    const float* __restrict__ A_log, const float* __restrict__ Dp,
    float* __restrict__ P, float* __restrict__ Q,
    const float* __restrict__ Hin, unsigned short* __restrict__ y)
{
    const int bid  = blockIdx.x;
    const int c    = bid & (N_CHUNK - 1);
    const int rest = bid >> 5;
    const int b    = rest >> 3;
    const int dgrp = rest & 7;
    const int d    = dgrp * 256 + threadIdx.x;
    const int t0   = c * CLEN;

    float nA[16];
    #pragma unroll
    for (int k = 0; k < 4; ++k) {
        const float4 a4 = *(const float4*)(A_log + (size_t)d * 16 + k * 4);
        nA[4 * k + 0] = -__expf(a4.x);
        nA[4 * k + 1] = -__expf(a4.y);
        nA[4 * k + 2] = -__expf(a4.z);
        nA[4 * k + 3] = -__expf(a4.w);
    }

    const size_t sbase = (((size_t)(b * N_CHUNK + c)) << 15) + ((size_t)d << 4);

    float h[16], Pacc[16];
    if (PHASE == 0) {
        #pragma unroll
        for (int n = 0; n < 16; ++n) { h[n] = 0.f; Pacc[n] = 1.f; }
    } else {
        #pragma unroll
        for (int k = 0; k < 4; ++k) {
            const float4 h4 = *(const float4*)(Hin + sbase + k * 4);
            h[4 * k + 0] = h4.x; h[4 * k + 1] = h4.y;
            h[4 * k + 2] = h4.z; h[4 * k + 3] = h4.w;
        }
    }
    const float Dd = (PHASE == 1) ? Dp[d] : 0.f;

    #pragma unroll 2
    for (int t = 0; t < CLEN; ++t) {
        const size_t m = (size_t)b * L_SEQ + t0 + t;
        const float dt_v = b2f(delta_bf[m * D_INNER + d]);
        const float u_v  = b2f(u_bf[m * D_INNER + d]);
        const float dtu  = dt_v * u_v;
        const float* sB = xdbl + m * 96 + DT_RANK;   // wave-uniform -> s_load
        const float* sC = sB + D_STATE;

        float v = u_v * Dd;
        #pragma unroll
        for (int n = 0; n < 16; ++n) {
            const float dA = __expf(dt_v * nA[n]);
            if (PHASE == 0) Pacc[n] *= dA;
            h[n] = fmaf(dA, h[n], dtu * sB[n]);
            if (PHASE == 1) v = fmaf(h[n], sC[n], v);
        }
        if (PHASE == 1) {
            const float z   = b2f(xz_bf[m * (2 * D_INNER) + D_INNER + d]);
            const float sig = 1.f / (1.f + __expf(-z));
            y[m * D_INNER + d] = f2b(v * z * sig);
        }
    }

    if (PHASE == 0) {
        #pragma unroll
        for (int k = 0; k < 4; ++k) {
            *(float4*)(P + sbase + k * 4) =
                make_float4(Pacc[4*k], Pacc[4*k+1], Pacc[4*k+2], Pacc[4*k+3]);
            *(float4*)(Q + sbase + k * 4) =
                make_float4(h[4*k], h[4*k+1], h[4*k+2], h[4*k+3]);
        }
    }
}

// ---------------------------------------------------------------------------
// Sequential chunk composition: h_in[c] for each (b,d,n).
// ---------------------------------------------------------------------------
__global__ __launch_bounds__(256) void scan_combine_kernel(
    const float* __restrict__ P, const float* __restrict__ Q,
    float* __restrict__ Hin)
{
    const int idx = blockIdx.x * 256 + threadIdx.x;
    const int b   = idx >> 15;
    const int dn  = idx & 32767;
    float h = 0.f;
    #pragma unroll
    for (int c = 0; c < N_CHUNK; ++c) {
        const size_t o = ((size_t)(b * N_CHUNK + c) << 15) + dn;
        Hin[o] = h;
        h = fmaf(P[o], h, Q[o]);
    }
}

// ---------------------------------------------------------------------------
// Launch
// ---------------------------------------------------------------------------
extern "C" void kernel_launch(void* const* d_in, const int* in_sizes, int n_in,
                              void* d_out, int out_size, void* d_ws, size_t ws_size,
                              hipStream_t stream)
{
    const float* hs        = (const float*)d_in[0];
    const float* in_proj_w = (const float*)d_in[1];
    const float* conv_w    = (const float*)d_in[2];
    const float* conv_b    = (const float*)d_in[3];
    const float* x_proj_w  = (const float*)d_in[4];
    const float* dt_proj_w = (const float*)d_in[5];
    const float* dt_proj_b = (const float*)d_in[6];
    const float* A_log     = (const float*)d_in[7];
    const float* D_param   = (const float*)d_in[8];
    const float* out_proj_w= (const float*)d_in[9];
    float* out = (float*)d_out;

    // ---- workspace layout ----
    unsigned short* xz_bf  = (unsigned short*)d_ws;                     // 4096*4096 us (33.5MB)
    unsigned short* u_bf   = xz_bf + (size_t)M_ROWS * 2 * D_INNER;      // 4096*2048 us
    float* xdbl            = (float*)(u_bf + (size_t)M_ROWS * D_INNER); // 4096*96 f
    unsigned short* dt_bf  = (unsigned short*)(xdbl + (size_t)M_ROWS * 96);  // 4096*64 us
    unsigned short* delta_bf = dt_bf + (size_t)M_ROWS * DT_RANK;        // 4096*2048 us (16.8MB)
    float* Pws   = (float*)(delta_bf + (size_t)M_ROWS * D_INNER);       // 8.4MB
    float* Qws   = Pws + (size_t)N_BATCH * N_CHUNK * D_INNER * 16;
    float* Hin   = Qws + (size_t)N_BATCH * N_CHUNK * D_INNER * 16;
    unsigned short* opw_bf = (unsigned short*)(Hin + (size_t)N_BATCH * N_CHUNK * D_INNER * 16);
    unsigned short* y_bf   = opw_bf + (size_t)D_MODEL * D_INNER;        // 16.8MB
    unsigned short* xpw_bf = y_bf   + (size_t)M_ROWS * D_INNER;
    unsigned short* dtw_bf = xpw_bf + (size_t)128 * D_INNER;
    // aliases (stream-ordered, non-overlapping lifetimes):
    unsigned short* hs_bf  = delta_bf;                         // dead after in_proj
    unsigned short* ipw_bf = hs_bf + (size_t)M_ROWS * D_MODEL; // dead after in_proj
    float* xp_part = (float*)y_bf;     // [8][4096][128] f32 = 16.8MB, dead after xproj_reduce
    float* op_part = (float*)xz_bf;    // [2][4096][1024] f32 = 33.5MB, xz dead after scan1

    const dim3 blk(256);

    // 0) fused fp32 -> bf16 casts (hs, in_proj_w, out_proj_w, x_proj_w pad, dt_proj_w)
    cvt_all_kernel<<<(N4_ALL + 255) / 256, blk, 0, stream>>>(
        hs, in_proj_w, out_proj_w, x_proj_w, dt_proj_w,
        hs_bf, ipw_bf, opw_bf, xpw_bf, dtw_bf);

    // 1) xz = hs @ in_proj_w^T   (bf16 MFMA, bf16 out)
    gemm_mfma_bt<0, unsigned short>
        <<<dim3((2 * D_INNER) / 128, M_ROWS / 128, 1), blk, 0, stream>>>(
        hs_bf, ipw_bf, xz_bf, nullptr, M_ROWS, 2 * D_INNER, D_MODEL, D_MODEL);

    // 2) u = silu(causal_conv(x) + conv_b)  (bf16 in/out)
    conv_silu_kernel<<<(M_ROWS * D_INNER) / 256, blk, 0, stream>>>(
        xz_bf, conv_w, conv_b, u_bf);

    // 3) x_dbl = u @ x_proj_w^T   (bf16 MFMA, split-K=8, padded N=128, fp32 partials)
    gemm_mfma_bt<0, float>
        <<<dim3(1, M_ROWS / 128, XP_KSPLIT), blk, 0, stream>>>(
        u_bf, xpw_bf, xp_part, nullptr, M_ROWS, 128, D_INNER, XP_KLEN);
    xproj_reduce_kernel<<<(M_ROWS * 24 + 255) / 256, blk, 0, stream>>>(
        xp_part, xdbl, dt_bf);

    // 4) delta = softplus(dt @ dt_proj_w^T + dt_proj_b)  (bf16 MFMA, bf16 out)
    gemm_mfma_bt<1, unsigned short>
        <<<dim3(D_INNER / 128, M_ROWS / 128, 1), blk, 0, stream>>>(
        dt_bf, dtw_bf, delta_bf, dt_proj_b, M_ROWS, D_INNER, DT_RANK, DT_RANK);

    // 5) chunked selective scan (register-sequential, no LDS)
    const int scan_blocks = N_BATCH * (D_INNER / 256) * N_CHUNK;  // 512
    scan_seq_kernel<0><<<scan_blocks, blk, 0, stream>>>(
        delta_bf, u_bf, xdbl, xz_bf, A_log, D_param, Pws, Qws, nullptr, nullptr);
    scan_combine_kernel<<<(N_BATCH * D_INNER * 16) / 256, blk, 0, stream>>>(
        Pws, Qws, Hin);
    scan_seq_kernel<1><<<scan_blocks, blk, 0, stream>>>(
        delta_bf, u_bf, xdbl, xz_bf, A_log, D_param, nullptr, nullptr, Hin, y_bf);

    // 6) out = y @ out_proj_w^T   (bf16 MFMA, split-K=2, fp32 partials)
    gemm_mfma_bt<0, float>
        <<<dim3(D_MODEL / 128, M_ROWS / 128, OP_KSPLIT), blk, 0, stream>>>(
        y_bf, opw_bf, op_part, nullptr, M_ROWS, D_MODEL, D_INNER, OP_KLEN);
    oproj_reduce_kernel<<<(M_ROWS * D_MODEL / 4 + 255) / 256, blk, 0, stream>>>(
        op_part, out);
}

// Round 8
// 356.561 us; speedup vs baseline: 1.1677x; 1.1677x over previous
//
#include <hip/hip_runtime.h>
#include <hip/hip_bf16.h>
#include <math.h>

#define D_MODEL 1024
#define D_STATE 16
#define D_CONV 4
#define D_INNER 2048
#define DT_RANK 64
#define L_SEQ 2048
#define N_BATCH 2
#define M_ROWS (N_BATCH * L_SEQ)   // 4096

#define N_CHUNK 32                 // chunks over L
#define CLEN (L_SEQ / N_CHUNK)     // 64 timesteps per chunk

#define XP_KSPLIT 8                // split-K factor for x_proj
#define XP_KLEN (D_INNER / XP_KSPLIT)  // 256
#define OP_KSPLIT 2                // split-K factor for out_proj
#define OP_KLEN (D_INNER / OP_KSPLIT)  // 1024

typedef __attribute__((ext_vector_type(8))) __bf16 bf16x8;
typedef __attribute__((ext_vector_type(4))) float f32x4;

__device__ __forceinline__ unsigned short f2b(float f) {
    unsigned int u = __float_as_uint(f);
    unsigned int r = (u + 0x7fffu + ((u >> 16) & 1u)) >> 16;   // RNE
    return (unsigned short)r;
}
__device__ __forceinline__ float b2f(unsigned short s) {
    return __uint_as_float((unsigned int)s << 16);
}
// fast softplus: max(x,0) + log(1+exp(-|x|)), branch-free, v_exp/v_log only
__device__ __forceinline__ float softplus_fast(float x) {
    const float ax = fabsf(x);
    return fmaxf(x, 0.f) + __logf(1.f + __expf(-ax));
}

// addrspace casts for global_load_lds
#define AS1G(p) ((const __attribute__((address_space(1))) void*)(uintptr_t)(p))
#define AS3L(p) ((__attribute__((address_space(3))) void*)(unsigned int)(uintptr_t)(p))

// ---------------------------------------------------------------------------
// Fused fp32 -> bf16 cast of all 5 weight/activation tensors (one launch).
// x_proj_w is padded 96 -> 128 rows (zeros).
// ---------------------------------------------------------------------------
#define N4_HS (M_ROWS * D_MODEL / 4)          // 1048576
#define N4_IP (2 * D_INNER * D_MODEL / 4)     // 2097152
#define N4_OP (D_MODEL * D_INNER / 4)         // 524288
#define N4_XP (128 * D_INNER / 4)             // 65536 (padded)
#define N4_DT (D_INNER * DT_RANK / 4)         // 32768
#define N4_ALL (N4_HS + N4_IP + N4_OP + N4_XP + N4_DT)

__device__ __forceinline__ void cvt4(const float* s, unsigned short* d, int i) {
    const float4 f = ((const float4*)s)[i];
    ushort4 o;
    o.x = f2b(f.x); o.y = f2b(f.y); o.z = f2b(f.z); o.w = f2b(f.w);
    ((ushort4*)d)[i] = o;
}

__global__ __launch_bounds__(256) void cvt_all_kernel(
    const float* __restrict__ hs,  const float* __restrict__ ipw,
    const float* __restrict__ opw, const float* __restrict__ xpw,
    const float* __restrict__ dtw,
    unsigned short* __restrict__ hs_bf,  unsigned short* __restrict__ ipw_bf,
    unsigned short* __restrict__ opw_bf, unsigned short* __restrict__ xpw_bf,
    unsigned short* __restrict__ dtw_bf)
{
    int i = blockIdx.x * 256 + threadIdx.x;
    if (i < N4_HS) { cvt4(hs, hs_bf, i); return; }
    i -= N4_HS;
    if (i < N4_IP) { cvt4(ipw, ipw_bf, i); return; }
    i -= N4_IP;
    if (i < N4_OP) { cvt4(opw, opw_bf, i); return; }
    i -= N4_OP;
    if (i < N4_XP) {
        const int row = (i * 4) >> 11;   // /2048
        ushort4 o;
        if (row < 96) {
            const float4 f = ((const float4*)xpw)[i];
            o.x = f2b(f.x); o.y = f2b(f.y); o.z = f2b(f.z); o.w = f2b(f.w);
        } else { o.x = o.y = o.z = o.w = 0; }
        ((ushort4*)xpw_bf)[i] = o;
        return;
    }
    i -= N4_XP;
    if (i < N4_DT) cvt4(dtw, dtw_bf, i);
}

// ---------------------------------------------------------------------------
// bf16 MFMA GEMM (m97 structure): C[M,N] = A[M,K]*B[N,K]^T.
// CT = float (fp32 out / split-K partials) or unsigned short (bf16 out).
// MODE 0: plain.  MODE 1: softplus(acc + bias[col])  (fast softplus).
// Split-K: blockIdx.z selects K-chunk [z*k_len,(z+1)*k_len), C += z*M*N.
// ---------------------------------------------------------------------------
template <int MODE, typename CT>
__global__ __launch_bounds__(256) void gemm_mfma_bt(
    const unsigned short* __restrict__ A, const unsigned short* __restrict__ B,
    CT* __restrict__ C, const float* __restrict__ bias,
    int M, int N, int K, int k_len)
{
    __shared__ unsigned short As[128 * 32];
    __shared__ unsigned short Bs[128 * 32];

    const int tid  = threadIdx.x;
    const int wave = tid >> 6;
    const int lane = tid & 63;
    const int row0 = blockIdx.y * 128;
    const int col0 = blockIdx.x * 128;
    const int kbeg = blockIdx.z * k_len;
    C += (size_t)blockIdx.z * M * N;
    const int wr = (wave >> 1) * 64;
    const int wc = (wave & 1) * 64;
    const int lm = lane & 15;
    const int kg = (lane >> 4) * 8;

    f32x4 acc[4][4];
    #pragma unroll
    for (int i = 0; i < 4; ++i)
        #pragma unroll
        for (int j = 0; j < 4; ++j)
            acc[i][j] = (f32x4){0.f, 0.f, 0.f, 0.f};

    const int c0 = tid;
    const int c1 = tid + 256;
    const int r0_ = c0 >> 2, kq0 = (c0 & 3) * 8;
    const int r1_ = c1 >> 2, kq1 = (c1 & 3) * 8;
    unsigned short* lA0 = As + wave * 512;
    unsigned short* lA1 = As + 2048 + wave * 512;
    unsigned short* lB0 = Bs + wave * 512;
    unsigned short* lB1 = Bs + 2048 + wave * 512;

    for (int k0 = kbeg; k0 < kbeg + k_len; k0 += 32) {
        __syncthreads();
        __builtin_amdgcn_global_load_lds(AS1G(A + (size_t)(row0 + r0_) * K + k0 + kq0), AS3L(lA0), 16, 0, 0);
        __builtin_amdgcn_global_load_lds(AS1G(A + (size_t)(row0 + r1_) * K + k0 + kq1), AS3L(lA1), 16, 0, 0);
        __builtin_amdgcn_global_load_lds(AS1G(B + (size_t)(col0 + r0_) * K + k0 + kq0), AS3L(lB0), 16, 0, 0);
        __builtin_amdgcn_global_load_lds(AS1G(B + (size_t)(col0 + r1_) * K + k0 + kq1), AS3L(lB1), 16, 0, 0);
        __syncthreads();

        bf16x8 af[4], bf[4];
        #pragma unroll
        for (int i = 0; i < 4; ++i) {
            af[i] = *(const bf16x8*)&As[(wr + i * 16 + lm) * 32 + kg];
            bf[i] = *(const bf16x8*)&Bs[(wc + i * 16 + lm) * 32 + kg];
        }
        #pragma unroll
        for (int i = 0; i < 4; ++i)
            #pragma unroll
            for (int j = 0; j < 4; ++j)
                acc[i][j] = __builtin_amdgcn_mfma_f32_16x16x32_bf16(af[i], bf[j], acc[i][j], 0, 0, 0);
    }

    // C/D mapping: col = lane&15, row = (lane>>4)*4 + reg
    #pragma unroll
    for (int j = 0; j < 4; ++j) {
        const int cc = col0 + wc + j * 16 + lm;
        const float bv = (MODE == 1) ? bias[cc] : 0.f;
        #pragma unroll
        for (int i = 0; i < 4; ++i) {
            const int r = row0 + wr + i * 16 + (lane >> 4) * 4;
            #pragma unroll
            for (int v = 0; v < 4; ++v) {
                float val = acc[i][j][v];
                if (MODE == 1) val = softplus_fast(val + bv);
                if (sizeof(CT) == 2)
                    C[(size_t)(r + v) * N + cc] = (CT)f2b(val);
                else
                    C[(size_t)(r + v) * N + cc] = (CT)val;
            }
        }
    }
}

// reduce x_proj split-K partials [XP_KSPLIT][M][128] -> xdbl [M][96] fp32
// and dt_bf [M][64] bf16 (columns 0..63).
__global__ __launch_bounds__(256) void xproj_reduce_kernel(
    const float* __restrict__ part, float* __restrict__ xdbl,
    unsigned short* __restrict__ dt_bf)
{
    const int i = blockIdx.x * 256 + threadIdx.x;   // over M * 24
    if (i >= M_ROWS * 24) return;
    const int m  = i / 24;
    const int j4 = (i - m * 24) * 4;
    f32x4 s = *(const f32x4*)(part + (size_t)m * 128 + j4);
    #pragma unroll
    for (int ks = 1; ks < XP_KSPLIT; ++ks)
        s += *(const f32x4*)(part + (size_t)ks * M_ROWS * 128 + (size_t)m * 128 + j4);
    *(f32x4*)(xdbl + (size_t)m * 96 + j4) = s;
    if (j4 < DT_RANK) {
        ushort4 o;
        o.x = f2b(s.x); o.y = f2b(s.y); o.z = f2b(s.z); o.w = f2b(s.w);
        *(ushort4*)(dt_bf + (size_t)m * DT_RANK + j4) = o;
    }
}

// reduce out_proj split-K partials [OP_KSPLIT][M][D_MODEL] -> out (fp32)
__global__ __launch_bounds__(256) void oproj_reduce_kernel(
    const float* __restrict__ part, float* __restrict__ out)
{
    const int i = blockIdx.x * 256 + threadIdx.x;   // over M*D_MODEL/4
    if (i >= M_ROWS * D_MODEL / 4) return;
    f32x4 s = ((const f32x4*)part)[i];
    #pragma unroll
    for (int ks = 1; ks < OP_KSPLIT; ++ks)
        s += ((const f32x4*)part)[(size_t)ks * (M_ROWS * D_MODEL / 4) + i];
    ((f32x4*)out)[i] = s;
}

// ---------------------------------------------------------------------------
// Depthwise causal conv (width 4) + bias + SiLU.  bf16 in (x half of xz),
// bf16 out.
// ---------------------------------------------------------------------------
__global__ __launch_bounds__(256) void conv_silu_kernel(
    const unsigned short* __restrict__ xz_bf, const float* __restrict__ conv_w,
    const float* __restrict__ conv_b, unsigned short* __restrict__ u_bf)
{
    const int idx = blockIdx.x * 256 + threadIdx.x;
    const int c  = idx & (D_INNER - 1);
    const int ml = idx >> 11;
    const int l  = ml & (L_SEQ - 1);
    float acc = conv_b[c];
    const float* w = conv_w + c * D_CONV;
    #pragma unroll
    for (int j = 0; j < D_CONV; ++j) {
        const int ll = l - (D_CONV - 1) + j;
        if (ll >= 0)
            acc = fmaf(b2f(xz_bf[(size_t)(ml - (D_CONV - 1) + j) * (2 * D_INNER) + c]), w[j], acc);
    }
    const float uv = acc / (1.f + __expf(-acc));
    u_bf[(size_t)ml * D_INNER + c] = f2b(uv);
}

// ---------------------------------------------------------------------------
// Sequential-register selective scan.  One lane owns one d channel and all 16
// states in registers.  delta: fp32; u/z: bf16; B/C: wave-uniform s_loads.
// ---------------------------------------------------------------------------
template <int PHASE>
__global__ __launch_bounds__(256) void scan_seq_kernel(
    const float* __restrict__ delta,
    const unsigned short* __restrict__ u_bf,
    const float* __restrict__ xdbl,  const unsigned short* __restrict__ xz_bf,
    const float* __restrict__ A_log, const float* __restrict__ Dp,
    float* __restrict__ P, float* __restrict__ Q,
    const float* __restrict__ Hin, unsigned short* __restrict__ y)
{
    const int bid  = blockIdx.x;
    const int c    = bid & (N_CHUNK - 1);
    const int rest = bid >> 5;
    const int b    = rest >> 3;
    const int dgrp = rest & 7;
    const int d    = dgrp * 256 + threadIdx.x;
    const int t0   = c * CLEN;

    float nA[16];
    #pragma unroll
    for (int k = 0; k < 4; ++k) {
        const float4 a4 = *(const float4*)(A_log + (size_t)d * 16 + k * 4);
        nA[4 * k + 0] = -__expf(a4.x);
        nA[4 * k + 1] = -__expf(a4.y);
        nA[4 * k + 2] = -__expf(a4.z);
        nA[4 * k + 3] = -__expf(a4.w);
    }

    const size_t sbase = (((size_t)(b * N_CHUNK + c)) << 15) + ((size_t)d << 4);

    float h[16], Pacc[16];
    if (PHASE == 0) {
        #pragma unroll
        for (int n = 0; n < 16; ++n) { h[n] = 0.f; Pacc[n] = 1.f; }
    } else {
        #pragma unroll
        for (int k = 0; k < 4; ++k) {
            const float4 h4 = *(const float4*)(Hin + sbase + k * 4);
            h[4 * k + 0] = h4.x; h[4 * k + 1] = h4.y;
            h[4 * k + 2] = h4.z; h[4 * k + 3] = h4.w;
        }
    }
    const float Dd = (PHASE == 1) ? Dp[d] : 0.f;

    #pragma unroll 2
    for (int t = 0; t < CLEN; ++t) {
        const size_t m = (size_t)b * L_SEQ + t0 + t;
        const float dt_v = delta[m * D_INNER + d];
        const float u_v  = b2f(u_bf[m * D_INNER + d]);
        const float dtu  = dt_v * u_v;
        const float* sB = xdbl + m * 96 + DT_RANK;   // wave-uniform -> s_load
        const float* sC = sB + D_STATE;

        float v = u_v * Dd;
        #pragma unroll
        for (int n = 0; n < 16; ++n) {
            const float dA = __expf(dt_v * nA[n]);
            if (PHASE == 0) Pacc[n] *= dA;
            h[n] = fmaf(dA, h[n], dtu * sB[n]);
            if (PHASE == 1) v = fmaf(h[n], sC[n], v);
        }
        if (PHASE == 1) {
            const float z   = b2f(xz_bf[m * (2 * D_INNER) + D_INNER + d]);
            const float sig = 1.f / (1.f + __expf(-z));
            y[m * D_INNER + d] = f2b(v * z * sig);
        }
    }

    if (PHASE == 0) {
        #pragma unroll
        for (int k = 0; k < 4; ++k) {
            *(float4*)(P + sbase + k * 4) =
                make_float4(Pacc[4*k], Pacc[4*k+1], Pacc[4*k+2], Pacc[4*k+3]);
            *(float4*)(Q + sbase + k * 4) =
                make_float4(h[4*k], h[4*k+1], h[4*k+2], h[4*k+3]);
        }
    }
}

// ---------------------------------------------------------------------------
// Sequential chunk composition: h_in[c] for each (b,d,n).
// ---------------------------------------------------------------------------
__global__ __launch_bounds__(256) void scan_combine_kernel(
    const float* __restrict__ P, const float* __restrict__ Q,
    float* __restrict__ Hin)
{
    const int idx = blockIdx.x * 256 + threadIdx.x;
    const int b   = idx >> 15;
    const int dn  = idx & 32767;
    float h = 0.f;
    #pragma unroll
    for (int c = 0; c < N_CHUNK; ++c) {
        const size_t o = ((size_t)(b * N_CHUNK + c) << 15) + dn;
        Hin[o] = h;
        h = fmaf(P[o], h, Q[o]);
    }
}

// ---------------------------------------------------------------------------
// Launch
// ---------------------------------------------------------------------------
extern "C" void kernel_launch(void* const* d_in, const int* in_sizes, int n_in,
                              void* d_out, int out_size, void* d_ws, size_t ws_size,
                              hipStream_t stream)
{
    const float* hs        = (const float*)d_in[0];
    const float* in_proj_w = (const float*)d_in[1];
    const float* conv_w    = (const float*)d_in[2];
    const float* conv_b    = (const float*)d_in[3];
    const float* x_proj_w  = (const float*)d_in[4];
    const float* dt_proj_w = (const float*)d_in[5];
    const float* dt_proj_b = (const float*)d_in[6];
    const float* A_log     = (const float*)d_in[7];
    const float* D_param   = (const float*)d_in[8];
    const float* out_proj_w= (const float*)d_in[9];
    float* out = (float*)d_out;

    // ---- workspace layout ----
    unsigned short* xz_bf  = (unsigned short*)d_ws;                     // 4096*4096 us (33.5MB)
    unsigned short* u_bf   = xz_bf + (size_t)M_ROWS * 2 * D_INNER;      // 4096*2048 us
    float* xdbl            = (float*)(u_bf + (size_t)M_ROWS * D_INNER); // 4096*96 f
    unsigned short* dt_bf  = (unsigned short*)(xdbl + (size_t)M_ROWS * 96);  // 4096*64 us
    float* delta           = (float*)(dt_bf + (size_t)M_ROWS * DT_RANK);     // 4096*2048 f (33.5MB)
    float* Pws   = delta + (size_t)M_ROWS * D_INNER;                    // 8.4MB
    float* Qws   = Pws + (size_t)N_BATCH * N_CHUNK * D_INNER * 16;
    float* Hin   = Qws + (size_t)N_BATCH * N_CHUNK * D_INNER * 16;
    unsigned short* opw_bf = (unsigned short*)(Hin + (size_t)N_BATCH * N_CHUNK * D_INNER * 16);
    unsigned short* y_bf   = opw_bf + (size_t)D_MODEL * D_INNER;        // 16.8MB
    unsigned short* xpw_bf = y_bf   + (size_t)M_ROWS * D_INNER;
    unsigned short* dtw_bf = xpw_bf + (size_t)128 * D_INNER;
    // aliases (stream-ordered, non-overlapping lifetimes):
    unsigned short* hs_bf  = (unsigned short*)delta;           // dead after in_proj
    unsigned short* ipw_bf = hs_bf + (size_t)M_ROWS * D_MODEL; // dead after in_proj
    float* xp_part = (float*)y_bf;     // [8][4096][128] f32 = 16.8MB, dead after xproj_reduce
    float* op_part = (float*)xz_bf;    // [2][4096][1024] f32 = 33.5MB, xz dead after scan1

    const dim3 blk(256);

    // 0) fused fp32 -> bf16 casts (hs, in_proj_w, out_proj_w, x_proj_w pad, dt_proj_w)
    cvt_all_kernel<<<(N4_ALL + 255) / 256, blk, 0, stream>>>(
        hs, in_proj_w, out_proj_w, x_proj_w, dt_proj_w,
        hs_bf, ipw_bf, opw_bf, xpw_bf, dtw_bf);

    // 1) xz = hs @ in_proj_w^T   (bf16 MFMA, bf16 out)
    gemm_mfma_bt<0, unsigned short>
        <<<dim3((2 * D_INNER) / 128, M_ROWS / 128, 1), blk, 0, stream>>>(
        hs_bf, ipw_bf, xz_bf, nullptr, M_ROWS, 2 * D_INNER, D_MODEL, D_MODEL);

    // 2) u = silu(causal_conv(x) + conv_b)  (bf16 in/out)
    conv_silu_kernel<<<(M_ROWS * D_INNER) / 256, blk, 0, stream>>>(
        xz_bf, conv_w, conv_b, u_bf);

    // 3) x_dbl = u @ x_proj_w^T   (bf16 MFMA, split-K=8, padded N=128, fp32 partials)
    gemm_mfma_bt<0, float>
        <<<dim3(1, M_ROWS / 128, XP_KSPLIT), blk, 0, stream>>>(
        u_bf, xpw_bf, xp_part, nullptr, M_ROWS, 128, D_INNER, XP_KLEN);
    xproj_reduce_kernel<<<(M_ROWS * 24 + 255) / 256, blk, 0, stream>>>(
        xp_part, xdbl, dt_bf);

    // 4) delta = softplus(dt @ dt_proj_w^T + dt_proj_b)  (bf16 MFMA, fp32 out)
    gemm_mfma_bt<1, float>
        <<<dim3(D_INNER / 128, M_ROWS / 128, 1), blk, 0, stream>>>(
        dt_bf, dtw_bf, delta, dt_proj_b, M_ROWS, D_INNER, DT_RANK, DT_RANK);

    // 5) chunked selective scan (register-sequential, no LDS)
    const int scan_blocks = N_BATCH * (D_INNER / 256) * N_CHUNK;  // 512
    scan_seq_kernel<0><<<scan_blocks, blk, 0, stream>>>(
        delta, u_bf, xdbl, xz_bf, A_log, D_param, Pws, Qws, nullptr, nullptr);
    scan_combine_kernel<<<(N_BATCH * D_INNER * 16) / 256, blk, 0, stream>>>(
        Pws, Qws, Hin);
    scan_seq_kernel<1><<<scan_blocks, blk, 0, stream>>>(
        delta, u_bf, xdbl, xz_bf, A_log, D_param, nullptr, nullptr, Hin, y_bf);

    // 6) out = y @ out_proj_w^T   (bf16 MFMA, split-K=2, fp32 partials)
    gemm_mfma_bt<0, float>
        <<<dim3(D_MODEL / 128, M_ROWS / 128, OP_KSPLIT), blk, 0, stream>>>(
        y_bf, opw_bf, op_part, nullptr, M_ROWS, D_MODEL, D_INNER, OP_KLEN);
    oproj_reduce_kernel<<<(M_ROWS * D_MODEL / 4 + 255) / 256, blk, 0, stream>>>(
        op_part, out);
}